// Round 1
// baseline (1312.381 us; speedup 1.0000x reference)
//
#include <hip/hip_runtime.h>
#include <math.h>
#include <stdint.h>
#include <stddef.h>

#define BLOCK  256
#define S4     4
#define F32    32
#define E16    16
#define LTOT   32
#define LSPLIT 4
#define LPB    (LTOT / LSPLIT)   // 8 kernels per block
#define EPSF   1e-8f
#define HPI    1.57079632679489662f

__device__ __forceinline__ float dot4(const float4 a, const float4 b) {
    return a.x*b.x + a.y*b.y + a.z*b.z + a.w*b.w;
}
__device__ __forceinline__ float sqd4(const float4 a, const float4 b) {
    float x = a.x-b.x, y = a.y-b.y, z = a.z-b.z, w = a.w-b.w;
    return x*x + y*y + z*z + w*w;
}
// d >= 0; d == 0 -> 1/0 = +inf -> atanf(inf) = pi/2 (matches jnp.arctan)
__device__ __forceinline__ float atan_inv(float d) {
    return atanf(1.0f / d);
}

__global__ __launch_bounds__(BLOCK, 2)
void kconv_kernel(const float* __restrict__ x_focal,
                  const float* __restrict__ p_focal,
                  const float* __restrict__ x_neighbor,
                  const float* __restrict__ p_neighbor,
                  const float* __restrict__ edge_attr_neighbor,
                  const float* __restrict__ x_center,
                  const float* __restrict__ x_support,
                  const float* __restrict__ edge_attr_support,
                  const float* __restrict__ p_support,
                  float* __restrict__ out, int N)
{
    // ---------------- L-side tables in LDS (~31 KB) ----------------
    __shared__ float s_xsup[LTOT*S4*F32];   // 16 KB raw x_support
    __shared__ float s_esup[LTOT*S4*E16];   //  8 KB raw edge_attr_support
    __shared__ float s_xc  [LTOT*F32];      //  4 KB x_center
    __shared__ float s_sqsup[LTOT];         // sum_{s,f} x_support^2 (perm-invariant)
    __shared__ float s_ncos[LTOT*16];       // pairwise cos(p_sup[a], p_sup[b]), eps-clamped norms
    __shared__ float s_nrm [LTOT*S4];       // raw ||p_support[l,t]||

    const int tid = threadIdx.x;

    // stage raw tables (contiguous float4 copies, coalesced)
    for (int i = tid; i < LTOT*S4*F32/4; i += BLOCK)
        ((float4*)s_xsup)[i] = ((const float4*)x_support)[i];
    for (int i = tid; i < LTOT*S4*E16/4; i += BLOCK)
        ((float4*)s_esup)[i] = ((const float4*)edge_attr_support)[i];
    for (int i = tid; i < LTOT*F32/4; i += BLOCK)
        ((float4*)s_xc)[i] = ((const float4*)x_center)[i];

    // derived per-l tables: one thread per l (reads global to avoid LDS stride conflicts)
    if (tid < LTOT) {
        const int l = tid;
        float s = 0.f;
        const float4* xs = (const float4*)(x_support + l*(S4*F32));
        #pragma unroll
        for (int c = 0; c < S4*F32/4; ++c) { float4 v = xs[c]; s += dot4(v, v); }
        s_sqsup[l] = s;

        float ps[S4][3];
        #pragma unroll
        for (int q = 0; q < S4; ++q)
            #pragma unroll
            for (int k = 0; k < 3; ++k)
                ps[q][k] = p_support[(l*S4 + q)*3 + k];
        float nr[S4], nc[S4];
        #pragma unroll
        for (int q = 0; q < S4; ++q) {
            nr[q] = sqrtf(ps[q][0]*ps[q][0] + ps[q][1]*ps[q][1] + ps[q][2]*ps[q][2]);
            s_nrm[l*S4 + q] = nr[q];
            nc[q] = fmaxf(nr[q], EPSF);
        }
        #pragma unroll
        for (int a = 0; a < S4; ++a)
            #pragma unroll
            for (int b = 0; b < S4; ++b) {
                float d = ps[a][0]*ps[b][0] + ps[a][1]*ps[b][1] + ps[a][2]*ps[b][2];
                s_ncos[l*16 + a*4 + b] = d / (nc[a]*nc[b]);
            }
    }
    __syncthreads();

    const int n = blockIdx.x * BLOCK + tid;
    if (n >= N) return;                       // after all barriers
    const int l0 = blockIdx.y * LPB;

    // ---------------- per-thread (per-n) data in registers ----------------
    float4 xn[S4*F32/4];                      // 128 f32: x_neighbor[n]
    const float4* xng = (const float4*)(x_neighbor + (size_t)n*(S4*F32));
    #pragma unroll
    for (int i = 0; i < S4*F32/4; ++i) xn[i] = xng[i];
    float sq_nei = 0.f;
    #pragma unroll
    for (int i = 0; i < S4*F32/4; ++i) sq_nei += dot4(xn[i], xn[i]);

    float4 ev[S4*E16/4];                      // 64 f32: edge_attr_neighbor[n]
    const float4* evg = (const float4*)(edge_attr_neighbor + (size_t)n*(S4*E16));
    #pragma unroll
    for (int i = 0; i < S4*E16/4; ++i) ev[i] = evg[i];

    float pf[3], pn[S4][3];
    #pragma unroll
    for (int k = 0; k < 3; ++k) pf[k] = p_focal[n*3 + k];
    #pragma unroll
    for (int s = 0; s < S4; ++s)
        #pragma unroll
        for (int k = 0; k < 3; ++k)
            pn[s][k] = p_neighbor[((size_t)n*S4 + s)*3 + k] - pf[k];

    float len_nei[S4], inn[S4];
    #pragma unroll
    for (int s = 0; s < S4; ++s)
        len_nei[s] = sqrtf(pn[s][0]*pn[s][0] + pn[s][1]*pn[s][1] + pn[s][2]*pn[s][2]);
    #pragma unroll
    for (int s = 0; s < S4; ++s) {
        const int a = (s + 3) & 3;            // roll(+1): q[s] = p[s-1]
        float d = pn[a][0]*pn[s][0] + pn[a][1]*pn[s][1] + pn[a][2]*pn[s][2];
        inn[s] = d / (fmaxf(len_nei[a], EPSF) * fmaxf(len_nei[s], EPSF));
    }

    const float4* xfg = (const float4*)(x_focal + (size_t)n*F32);  // re-read per l (L1-hot)

    // lexicographic permutations of (0,1,2,3), as itertools.permutations
    constexpr int PERM[24][4] = {
        {0,1,2,3},{0,1,3,2},{0,2,1,3},{0,2,3,1},{0,3,1,2},{0,3,2,1},
        {1,0,2,3},{1,0,3,2},{1,2,0,3},{1,2,3,0},{1,3,0,2},{1,3,2,0},
        {2,0,1,3},{2,0,3,1},{2,1,0,3},{2,1,3,0},{2,3,0,1},{2,3,1,0},
        {3,0,1,2},{3,0,2,1},{3,1,0,2},{3,1,2,0},{3,2,0,1},{3,2,1,0}
    };

    #pragma unroll 1
    for (int li = 0; li < LPB; ++li) {
        const int l = l0 + li;

        // ---- 4x4 pairwise dots: dot[s][t] = x_nei[s,:] . x_sup[l,t,:] ----
        float acc[S4][S4];
        #pragma unroll
        for (int s = 0; s < S4; ++s)
            #pragma unroll
            for (int t = 0; t < S4; ++t) acc[s][t] = 0.f;

        const float4* supb = (const float4*)(s_xsup + l*(S4*F32));
        #pragma unroll
        for (int c = 0; c < F32/4; ++c) {
            float4 sv0 = supb[0*(F32/4) + c];  // broadcast LDS reads (uniform addr)
            float4 sv1 = supb[1*(F32/4) + c];
            float4 sv2 = supb[2*(F32/4) + c];
            float4 sv3 = supb[3*(F32/4) + c];
            #pragma unroll
            for (int s = 0; s < S4; ++s) {
                float4 xv = xn[s*(F32/4) + c];
                acc[s][0] += dot4(xv, sv0);
                acc[s][1] += dot4(xv, sv1);
                acc[s][2] += dot4(xv, sv2);
                acc[s][3] += dot4(xv, sv3);
            }
        }

        // ---- fold 24 perms: d = max(sq_nei + sq_sup - 2*cross, 0); argmin d ----
        const float base = sq_nei + s_sqsup[l];
        float best_d = 3.4e38f;
        uint32_t best_pk = 0u;
        #pragma unroll
        for (int p = 0; p < 24; ++p) {
            float cross = acc[0][PERM[p][0]] + acc[1][PERM[p][1]]
                        + acc[2][PERM[p][2]] + acc[3][PERM[p][3]];
            float d = fmaxf(base - 2.0f*cross, 0.0f);
            uint32_t pk = (uint32_t)PERM[p][0] | ((uint32_t)PERM[p][1] << 8)
                        | ((uint32_t)PERM[p][2] << 16) | ((uint32_t)PERM[p][3] << 24);
            if (d < best_d) { best_d = d; best_pk = pk; }   // first-occurrence argmin
        }
        const float sup_sc = atan_inv(best_d);

        int pm[S4];
        pm[0] = (int)( best_pk        & 3u);
        pm[1] = (int)((best_pk >> 8)  & 3u);
        pm[2] = (int)((best_pk >> 16) & 3u);
        pm[3] = (int)((best_pk >> 24) & 3u);

        // ---- angle score ----
        float ad = 0.f;
        #pragma unroll
        for (int s = 0; s < S4; ++s) {
            const int a = (s + 3) & 3;
            float cs = s_ncos[l*16 + pm[a]*4 + pm[s]];
            float df = inn[s] - cs;
            ad += df*df;
        }
        const float ang_sc = atan_inv(ad);

        // ---- length score ----
        float ldist = 0.f;
        #pragma unroll
        for (int s = 0; s < S4; ++s) {
            float df = len_nei[s] - s_nrm[l*S4 + pm[s]];
            ldist += df*df;
        }
        const float len_sc = atan_inv(ldist);

        // ---- edge score (direct squared diff, best perm rows from LDS) ----
        float edist = 0.f;
        #pragma unroll
        for (int s = 0; s < S4; ++s) {
            const float4* er = (const float4*)(s_esup + (l*S4 + pm[s])*E16);
            #pragma unroll
            for (int c = 0; c < E16/4; ++c)
                edist += sqd4(ev[s*(E16/4) + c], er[c]);
        }
        const float edg_sc = atan_inv(edist);

        // ---- center score (direct squared diff; x_focal re-read, L1-resident) ----
        float cd = 0.f;
        const float4* xcv = (const float4*)(s_xc + l*F32);
        #pragma unroll
        for (int c = 0; c < F32/4; ++c) cd += sqd4(xfg[c], xcv[c]);
        const float cen_sc = atan_inv(cd);

        // ---- total ----
        float t0 = len_sc - HPI, t1 = ang_sc - HPI, t2 = sup_sc - HPI,
              t3 = cen_sc - HPI, t4 = edg_sc - HPI;
        float total = t0*t0 + t1*t1 + t2*t2 + t3*t3 + t4*t4;
        out[(size_t)l*N + n] = atan_inv(total);
    }
}

extern "C" void kernel_launch(void* const* d_in, const int* in_sizes, int n_in,
                              void* d_out, int out_size, void* d_ws, size_t ws_size,
                              hipStream_t stream) {
    const float* x_focal            = (const float*)d_in[0];
    const float* p_focal            = (const float*)d_in[1];
    const float* x_neighbor         = (const float*)d_in[2];
    const float* p_neighbor         = (const float*)d_in[3];
    const float* edge_attr_neighbor = (const float*)d_in[4];
    const float* x_center           = (const float*)d_in[5];
    const float* x_support          = (const float*)d_in[6];
    const float* edge_attr_support  = (const float*)d_in[7];
    const float* p_support          = (const float*)d_in[8];
    float* outp = (float*)d_out;

    const int N = in_sizes[0] / F32;          // x_focal is [N, 32]
    dim3 grid((N + BLOCK - 1) / BLOCK, LSPLIT);
    hipLaunchKernelGGL(kconv_kernel, grid, dim3(BLOCK), 0, stream,
                       x_focal, p_focal, x_neighbor, p_neighbor, edge_attr_neighbor,
                       x_center, x_support, edge_attr_support, p_support, outp, N);
}

// Round 2
// 832.253 us; speedup vs baseline: 1.5769x; 1.5769x over previous
//
#include <hip/hip_runtime.h>
#include <math.h>
#include <stdint.h>
#include <stddef.h>

#define BLOCK  256
#define S4     4
#define F32    32
#define E16    16
#define E16P   20               // padded LDS row (spreads perm-gathered reads)
#define LTOT   32
#define LSPLIT 8
#define LPB    (LTOT / LSPLIT)  // 4 kernels per block
#define EPSF   1e-8f
#define HPI    1.57079632679489662f

__device__ __forceinline__ float dot4(const float4 a, const float4 b) {
    return a.x*b.x + a.y*b.y + a.z*b.z + a.w*b.w;
}
__device__ __forceinline__ float sqd4(const float4 a, const float4 b) {
    float x = a.x-b.x, y = a.y-b.y, z = a.z-b.z, w = a.w-b.w;
    return x*x + y*y + z*z + w*w;
}
// d >= 0; d == 0 -> 1/0 = +inf -> atanf(inf) = pi/2 (matches jnp.arctan)
__device__ __forceinline__ float atan_inv(float d) {
    return atanf(1.0f / d);
}

__global__ __launch_bounds__(BLOCK, 4)
void kconv_kernel(const float* __restrict__ x_focal,
                  const float* __restrict__ p_focal,
                  const float* __restrict__ x_neighbor,
                  const float* __restrict__ p_neighbor,
                  const float* __restrict__ edge_attr_neighbor,
                  const float* __restrict__ x_center,
                  const float* __restrict__ x_support,
                  const float* __restrict__ edge_attr_support,
                  const float* __restrict__ p_support,
                  float* __restrict__ out, int N)
{
    // ---- L-side tables for THIS block's LPB kernels only (~4 KB LDS) ----
    __shared__ float s_xsup [LPB*S4*F32];   // 2 KB
    __shared__ float s_esup [LPB*S4*E16P];  // 1.25 KB (padded rows)
    __shared__ float s_xc   [LPB*F32];      // 0.5 KB
    __shared__ float s_sqsup[LPB];
    __shared__ float s_ncos [LPB*16];       // pairwise cos table (symmetric)
    __shared__ float s_nrm  [LPB*S4];

    const int tid = threadIdx.x;
    const int l0  = blockIdx.y * LPB;

    for (int i = tid; i < LPB*S4*F32/4; i += BLOCK)
        ((float4*)s_xsup)[i] = ((const float4*)(x_support + l0*S4*F32))[i];
    for (int i = tid; i < LPB*S4*(E16/4); i += BLOCK) {
        const int row = i / (E16/4), c = i % (E16/4);
        ((float4*)(s_esup + row*E16P))[c] =
            ((const float4*)(edge_attr_support + (l0*S4 + row)*E16))[c];
    }
    for (int i = tid; i < LPB*F32/4; i += BLOCK)
        ((float4*)s_xc)[i] = ((const float4*)(x_center + l0*F32))[i];

    if (tid < LPB) {
        const int l = l0 + tid;
        float s = 0.f;
        const float4* xs = (const float4*)(x_support + l*(S4*F32));
        #pragma unroll
        for (int c = 0; c < S4*F32/4; ++c) { float4 v = xs[c]; s += dot4(v, v); }
        s_sqsup[tid] = s;

        float ps[S4][3];
        #pragma unroll
        for (int q = 0; q < S4; ++q)
            #pragma unroll
            for (int k = 0; k < 3; ++k)
                ps[q][k] = p_support[(l*S4 + q)*3 + k];
        float nr[S4], nc[S4];
        #pragma unroll
        for (int q = 0; q < S4; ++q) {
            nr[q] = sqrtf(ps[q][0]*ps[q][0] + ps[q][1]*ps[q][1] + ps[q][2]*ps[q][2]);
            s_nrm[tid*S4 + q] = nr[q];
            nc[q] = fmaxf(nr[q], EPSF);
        }
        #pragma unroll
        for (int a = 0; a < S4; ++a)
            #pragma unroll
            for (int b = 0; b < S4; ++b) {
                float d = ps[a][0]*ps[b][0] + ps[a][1]*ps[b][1] + ps[a][2]*ps[b][2];
                s_ncos[tid*16 + a*4 + b] = d / (nc[a]*nc[b]);
            }
    }
    __syncthreads();

    const int n = blockIdx.x * BLOCK + tid;
    if (n >= N) return;                     // no barriers after this point

    // ---- Phase 0: geometry (small persistent state) ----
    float pf[3], pnv[S4][3];
    #pragma unroll
    for (int k = 0; k < 3; ++k) pf[k] = p_focal[n*3 + k];
    #pragma unroll
    for (int s = 0; s < S4; ++s)
        #pragma unroll
        for (int k = 0; k < 3; ++k)
            pnv[s][k] = p_neighbor[((size_t)n*S4 + s)*3 + k] - pf[k];

    float len_nei[S4], inn[S4];
    #pragma unroll
    for (int s = 0; s < S4; ++s)
        len_nei[s] = sqrtf(pnv[s][0]*pnv[s][0] + pnv[s][1]*pnv[s][1] + pnv[s][2]*pnv[s][2]);
    #pragma unroll
    for (int s = 0; s < S4; ++s) {
        const int a = (s + 3) & 3;          // roll(+1): q[s] = p[s-1]
        float d = pnv[a][0]*pnv[s][0] + pnv[a][1]*pnv[s][1] + pnv[a][2]*pnv[s][2];
        inn[s] = d / (fmaxf(len_nei[a], EPSF) * fmaxf(len_nei[s], EPSF));
    }

    // ---- Phase 1: streamed 4x4 pairwise dots for all LPB l's ----
    float acc[LPB][S4][S4];
    #pragma unroll
    for (int li = 0; li < LPB; ++li)
        #pragma unroll
        for (int s = 0; s < S4; ++s)
            #pragma unroll
            for (int t = 0; t < S4; ++t) acc[li][s][t] = 0.f;

    float sq_nei = 0.f;
    const float4* xng  = (const float4*)(x_neighbor + (size_t)n*(S4*F32));
    const float4* sup4 = (const float4*)s_xsup;
    #pragma unroll
    for (int c = 0; c < F32/4; ++c) {
        float4 xv0 = xng[0*(F32/4) + c];
        float4 xv1 = xng[1*(F32/4) + c];
        float4 xv2 = xng[2*(F32/4) + c];
        float4 xv3 = xng[3*(F32/4) + c];
        sq_nei += dot4(xv0,xv0) + dot4(xv1,xv1) + dot4(xv2,xv2) + dot4(xv3,xv3);
        #pragma unroll
        for (int li = 0; li < LPB; ++li) {
            #pragma unroll
            for (int t = 0; t < S4; ++t) {
                float4 sv = sup4[(li*S4 + t)*(F32/4) + c];  // wave-uniform: broadcast
                acc[li][0][t] += dot4(xv0, sv);
                acc[li][1][t] += dot4(xv1, sv);
                acc[li][2][t] += dot4(xv2, sv);
                acc[li][3][t] += dot4(xv3, sv);
            }
        }
    }

    // lexicographic permutations of (0,1,2,3) (itertools.permutations order)
    constexpr int PERM[24][4] = {
        {0,1,2,3},{0,1,3,2},{0,2,1,3},{0,2,3,1},{0,3,1,2},{0,3,2,1},
        {1,0,2,3},{1,0,3,2},{1,2,0,3},{1,2,3,0},{1,3,0,2},{1,3,2,0},
        {2,0,1,3},{2,0,3,1},{2,1,0,3},{2,1,3,0},{2,3,0,1},{2,3,1,0},
        {3,0,1,2},{3,0,2,1},{3,1,0,2},{3,1,2,0},{3,2,0,1},{3,2,1,0}
    };

    // ---- Phase 2: perm fold + support/angle/length scores; acc dies here ----
    float    pt [LPB];
    uint32_t pks[LPB];
    #pragma unroll
    for (int li = 0; li < LPB; ++li) {
        const float base = sq_nei + s_sqsup[li];
        float best_d = 3.4e38f;
        uint32_t best_pk = 0u;
        #pragma unroll
        for (int p = 0; p < 24; ++p) {
            float cross = acc[li][0][PERM[p][0]] + acc[li][1][PERM[p][1]]
                        + acc[li][2][PERM[p][2]] + acc[li][3][PERM[p][3]];
            float d = fmaxf(base - 2.0f*cross, 0.0f);
            uint32_t pk = (uint32_t)PERM[p][0] | ((uint32_t)PERM[p][1] << 8)
                        | ((uint32_t)PERM[p][2] << 16) | ((uint32_t)PERM[p][3] << 24);
            if (d < best_d) { best_d = d; best_pk = pk; }   // first-occurrence argmin
        }
        const float sup_sc = atan_inv(best_d);

        int pm[S4];
        pm[0] = (int)( best_pk        & 3u);
        pm[1] = (int)((best_pk >> 8)  & 3u);
        pm[2] = (int)((best_pk >> 16) & 3u);
        pm[3] = (int)((best_pk >> 24) & 3u);

        float ad = 0.f;
        #pragma unroll
        for (int s = 0; s < S4; ++s) {
            const int a = (s + 3) & 3;
            float cs = s_ncos[li*16 + pm[a]*4 + pm[s]];
            float df = inn[s] - cs;
            ad += df*df;
        }
        const float ang_sc = atan_inv(ad);

        float ldist = 0.f;
        #pragma unroll
        for (int s = 0; s < S4; ++s) {
            float df = len_nei[s] - s_nrm[li*S4 + pm[s]];
            ldist += df*df;
        }
        const float len_sc = atan_inv(ldist);

        float t0 = len_sc - HPI, t1 = ang_sc - HPI, t2 = sup_sc - HPI;
        pt [li] = t0*t0 + t1*t1 + t2*t2;
        pks[li] = best_pk;
    }

    // ---- Phase 3: edge score (ev transient; acc already dead) ----
    {
        float4 ev[S4*E16/4];
        const float4* evg = (const float4*)(edge_attr_neighbor + (size_t)n*(S4*E16));
        #pragma unroll
        for (int i = 0; i < S4*E16/4; ++i) ev[i] = evg[i];

        #pragma unroll
        for (int li = 0; li < LPB; ++li) {
            const uint32_t pk = pks[li];
            int pm[S4];
            pm[0] = (int)( pk        & 3u);
            pm[1] = (int)((pk >> 8)  & 3u);
            pm[2] = (int)((pk >> 16) & 3u);
            pm[3] = (int)((pk >> 24) & 3u);
            float edist = 0.f;
            #pragma unroll
            for (int s = 0; s < S4; ++s) {
                const float4* er = (const float4*)(s_esup + (li*S4 + pm[s])*E16P);
                #pragma unroll
                for (int c = 0; c < E16/4; ++c)
                    edist += sqd4(ev[s*(E16/4) + c], er[c]);
            }
            float te = atan_inv(edist) - HPI;
            pt[li] += te*te;
        }
    }

    // ---- Phase 4: center score (streamed) + final ----
    {
        float cd[LPB];
        #pragma unroll
        for (int li = 0; li < LPB; ++li) cd[li] = 0.f;
        const float4* xfg = (const float4*)(x_focal + (size_t)n*F32);
        const float4* xc4 = (const float4*)s_xc;
        #pragma unroll
        for (int c = 0; c < F32/4; ++c) {
            float4 xf = xfg[c];
            #pragma unroll
            for (int li = 0; li < LPB; ++li)
                cd[li] += sqd4(xf, xc4[li*(F32/4) + c]);
        }
        #pragma unroll
        for (int li = 0; li < LPB; ++li) {
            float tc = atan_inv(cd[li]) - HPI;
            float total = pt[li] + tc*tc;
            out[(size_t)(l0 + li)*N + n] = atan_inv(total);
        }
    }
}

extern "C" void kernel_launch(void* const* d_in, const int* in_sizes, int n_in,
                              void* d_out, int out_size, void* d_ws, size_t ws_size,
                              hipStream_t stream) {
    const float* x_focal            = (const float*)d_in[0];
    const float* p_focal            = (const float*)d_in[1];
    const float* x_neighbor         = (const float*)d_in[2];
    const float* p_neighbor         = (const float*)d_in[3];
    const float* edge_attr_neighbor = (const float*)d_in[4];
    const float* x_center           = (const float*)d_in[5];
    const float* x_support          = (const float*)d_in[6];
    const float* edge_attr_support  = (const float*)d_in[7];
    const float* p_support          = (const float*)d_in[8];
    float* outp = (float*)d_out;

    const int N = in_sizes[0] / F32;        // x_focal is [N, 32]
    dim3 grid((N + BLOCK - 1) / BLOCK, LSPLIT);
    hipLaunchKernelGGL(kconv_kernel, grid, dim3(BLOCK), 0, stream,
                       x_focal, p_focal, x_neighbor, p_neighbor, edge_attr_neighbor,
                       x_center, x_support, edge_attr_support, p_support, outp, N);
}

// Round 3
// 419.871 us; speedup vs baseline: 3.1257x; 1.9822x over previous
//
#include <hip/hip_runtime.h>
#include <math.h>
#include <stdint.h>
#include <stddef.h>

#define BLOCK  256
#define S4     4
#define F32    32
#define E16    16
#define E16P   20               // padded LDS row (spreads perm-gathered reads)
#define LTOT   32
#define LSPLIT 8
#define LPB    (LTOT / LSPLIT)  // 4 kernels per block
#define EPSF   1e-8f
#define HPI    1.57079632679489662f

__device__ __forceinline__ float dot4(const float4 a, const float4 b) {
    return a.x*b.x + a.y*b.y + a.z*b.z + a.w*b.w;
}
__device__ __forceinline__ float sqd4(const float4 a, const float4 b) {
    float x = a.x-b.x, y = a.y-b.y, z = a.z-b.z, w = a.w-b.w;
    return x*x + y*y + z*z + w*w;
}
// d >= 0; d == 0 -> 1/0 = +inf -> atanf(inf) = pi/2 (matches jnp.arctan)
__device__ __forceinline__ float atan_inv(float d) {
    return atanf(1.0f / d);
}

// min 2 waves/EU -> 256-VGPR budget. Live set ~110 regs; round-2's (256,4)
// budgeted 128 but allocated 64 and spilled 2.4 GB of scratch. Do NOT raise.
__global__ __launch_bounds__(BLOCK, 2)
void kconv_kernel(const float* __restrict__ x_focal,
                  const float* __restrict__ p_focal,
                  const float* __restrict__ x_neighbor,
                  const float* __restrict__ p_neighbor,
                  const float* __restrict__ edge_attr_neighbor,
                  const float* __restrict__ x_center,
                  const float* __restrict__ x_support,
                  const float* __restrict__ edge_attr_support,
                  const float* __restrict__ p_support,
                  float* __restrict__ out, int N)
{
    // ---- L-side tables for THIS block's LPB kernels only (~4 KB LDS) ----
    __shared__ float s_xsup [LPB*S4*F32];   // 2 KB
    __shared__ float s_esup [LPB*S4*E16P];  // 1.25 KB (padded rows)
    __shared__ float s_xc   [LPB*F32];      // 0.5 KB
    __shared__ float s_sqsup[LPB];
    __shared__ float s_ncos [LPB*16];       // pairwise cos table
    __shared__ float s_nrm  [LPB*S4];

    const int tid = threadIdx.x;
    const int l0  = blockIdx.y * LPB;

    for (int i = tid; i < LPB*S4*F32/4; i += BLOCK)
        ((float4*)s_xsup)[i] = ((const float4*)(x_support + l0*S4*F32))[i];
    for (int i = tid; i < LPB*S4*(E16/4); i += BLOCK) {
        const int row = i / (E16/4), c = i % (E16/4);
        ((float4*)(s_esup + row*E16P))[c] =
            ((const float4*)(edge_attr_support + (l0*S4 + row)*E16))[c];
    }
    for (int i = tid; i < LPB*F32/4; i += BLOCK)
        ((float4*)s_xc)[i] = ((const float4*)(x_center + l0*F32))[i];

    if (tid < LPB) {
        const int l = l0 + tid;
        float s = 0.f;
        const float4* xs = (const float4*)(x_support + l*(S4*F32));
        #pragma unroll
        for (int c = 0; c < S4*F32/4; ++c) { float4 v = xs[c]; s += dot4(v, v); }
        s_sqsup[tid] = s;

        float ps[S4][3];
        #pragma unroll
        for (int q = 0; q < S4; ++q)
            #pragma unroll
            for (int k = 0; k < 3; ++k)
                ps[q][k] = p_support[(l*S4 + q)*3 + k];
        float nr[S4], nc[S4];
        #pragma unroll
        for (int q = 0; q < S4; ++q) {
            nr[q] = sqrtf(ps[q][0]*ps[q][0] + ps[q][1]*ps[q][1] + ps[q][2]*ps[q][2]);
            s_nrm[tid*S4 + q] = nr[q];
            nc[q] = fmaxf(nr[q], EPSF);
        }
        #pragma unroll
        for (int a = 0; a < S4; ++a)
            #pragma unroll
            for (int b = 0; b < S4; ++b) {
                float d = ps[a][0]*ps[b][0] + ps[a][1]*ps[b][1] + ps[a][2]*ps[b][2];
                s_ncos[tid*16 + a*4 + b] = d / (nc[a]*nc[b]);
            }
    }
    __syncthreads();

    const int n = blockIdx.x * BLOCK + tid;
    if (n >= N) return;                     // no barriers after this point

    // ---- Phase 0: geometry (small persistent state) ----
    float pf[3], pnv[S4][3];
    #pragma unroll
    for (int k = 0; k < 3; ++k) pf[k] = p_focal[n*3 + k];
    #pragma unroll
    for (int s = 0; s < S4; ++s)
        #pragma unroll
        for (int k = 0; k < 3; ++k)
            pnv[s][k] = p_neighbor[((size_t)n*S4 + s)*3 + k] - pf[k];

    float len_nei[S4], inn[S4];
    #pragma unroll
    for (int s = 0; s < S4; ++s)
        len_nei[s] = sqrtf(pnv[s][0]*pnv[s][0] + pnv[s][1]*pnv[s][1] + pnv[s][2]*pnv[s][2]);
    #pragma unroll
    for (int s = 0; s < S4; ++s) {
        const int a = (s + 3) & 3;          // roll(+1): q[s] = p[s-1]
        float d = pnv[a][0]*pnv[s][0] + pnv[a][1]*pnv[s][1] + pnv[a][2]*pnv[s][2];
        inn[s] = d / (fmaxf(len_nei[a], EPSF) * fmaxf(len_nei[s], EPSF));
    }

    // ---- Phase 1: streamed 4x4 pairwise dots for all LPB l's ----
    float acc[LPB][S4][S4];
    #pragma unroll
    for (int li = 0; li < LPB; ++li)
        #pragma unroll
        for (int s = 0; s < S4; ++s)
            #pragma unroll
            for (int t = 0; t < S4; ++t) acc[li][s][t] = 0.f;

    float sq_nei = 0.f;
    const float4* xng  = (const float4*)(x_neighbor + (size_t)n*(S4*F32));
    const float4* sup4 = (const float4*)s_xsup;
    #pragma unroll
    for (int c = 0; c < F32/4; ++c) {
        float4 xv0 = xng[0*(F32/4) + c];
        float4 xv1 = xng[1*(F32/4) + c];
        float4 xv2 = xng[2*(F32/4) + c];
        float4 xv3 = xng[3*(F32/4) + c];
        sq_nei += dot4(xv0,xv0) + dot4(xv1,xv1) + dot4(xv2,xv2) + dot4(xv3,xv3);
        #pragma unroll
        for (int li = 0; li < LPB; ++li) {
            #pragma unroll
            for (int t = 0; t < S4; ++t) {
                float4 sv = sup4[(li*S4 + t)*(F32/4) + c];  // wave-uniform: broadcast
                acc[li][0][t] += dot4(xv0, sv);
                acc[li][1][t] += dot4(xv1, sv);
                acc[li][2][t] += dot4(xv2, sv);
                acc[li][3][t] += dot4(xv3, sv);
            }
        }
    }

    // lexicographic permutations of (0,1,2,3) (itertools.permutations order)
    constexpr int PERM[24][4] = {
        {0,1,2,3},{0,1,3,2},{0,2,1,3},{0,2,3,1},{0,3,1,2},{0,3,2,1},
        {1,0,2,3},{1,0,3,2},{1,2,0,3},{1,2,3,0},{1,3,0,2},{1,3,2,0},
        {2,0,1,3},{2,0,3,1},{2,1,0,3},{2,1,3,0},{2,3,0,1},{2,3,1,0},
        {3,0,1,2},{3,0,2,1},{3,1,0,2},{3,1,2,0},{3,2,0,1},{3,2,1,0}
    };

    // ---- Phase 2: perm fold + support/angle/length scores; acc dies here ----
    float    pt [LPB];
    uint32_t pks[LPB];
    #pragma unroll
    for (int li = 0; li < LPB; ++li) {
        const float base = sq_nei + s_sqsup[li];
        float best_d = 3.4e38f;
        uint32_t best_pk = 0u;
        #pragma unroll
        for (int p = 0; p < 24; ++p) {
            float cross = acc[li][0][PERM[p][0]] + acc[li][1][PERM[p][1]]
                        + acc[li][2][PERM[p][2]] + acc[li][3][PERM[p][3]];
            float d = fmaxf(base - 2.0f*cross, 0.0f);
            uint32_t pk = (uint32_t)PERM[p][0] | ((uint32_t)PERM[p][1] << 8)
                        | ((uint32_t)PERM[p][2] << 16) | ((uint32_t)PERM[p][3] << 24);
            if (d < best_d) { best_d = d; best_pk = pk; }   // first-occurrence argmin
        }
        const float sup_sc = atan_inv(best_d);

        int pm[S4];
        pm[0] = (int)( best_pk        & 3u);
        pm[1] = (int)((best_pk >> 8)  & 3u);
        pm[2] = (int)((best_pk >> 16) & 3u);
        pm[3] = (int)((best_pk >> 24) & 3u);

        float ad = 0.f;
        #pragma unroll
        for (int s = 0; s < S4; ++s) {
            const int a = (s + 3) & 3;
            float cs = s_ncos[li*16 + pm[a]*4 + pm[s]];
            float df = inn[s] - cs;
            ad += df*df;
        }
        const float ang_sc = atan_inv(ad);

        float ldist = 0.f;
        #pragma unroll
        for (int s = 0; s < S4; ++s) {
            float df = len_nei[s] - s_nrm[li*S4 + pm[s]];
            ldist += df*df;
        }
        const float len_sc = atan_inv(ldist);

        float t0 = len_sc - HPI, t1 = ang_sc - HPI, t2 = sup_sc - HPI;
        pt [li] = t0*t0 + t1*t1 + t2*t2;
        pks[li] = best_pk;
    }

    // ---- Phase 3: edge score — slot-streamed, no 64-reg ev array ----
    {
        float ed[LPB];
        #pragma unroll
        for (int li = 0; li < LPB; ++li) ed[li] = 0.f;
        const float4* evg = (const float4*)(edge_attr_neighbor + (size_t)n*(S4*E16));
        #pragma unroll
        for (int s = 0; s < S4; ++s) {
            float4 e0 = evg[s*(E16/4) + 0];
            float4 e1 = evg[s*(E16/4) + 1];
            float4 e2 = evg[s*(E16/4) + 2];
            float4 e3 = evg[s*(E16/4) + 3];
            #pragma unroll
            for (int li = 0; li < LPB; ++li) {
                const int pm_s = (int)((pks[li] >> (8*s)) & 3u);
                const float4* er = (const float4*)(s_esup + (li*S4 + pm_s)*E16P);
                ed[li] += sqd4(e0, er[0]) + sqd4(e1, er[1])
                        + sqd4(e2, er[2]) + sqd4(e3, er[3]);
            }
        }
        #pragma unroll
        for (int li = 0; li < LPB; ++li) {
            float te = atan_inv(ed[li]) - HPI;
            pt[li] += te*te;
        }
    }

    // ---- Phase 4: center score (streamed) + final ----
    {
        float cd[LPB];
        #pragma unroll
        for (int li = 0; li < LPB; ++li) cd[li] = 0.f;
        const float4* xfg = (const float4*)(x_focal + (size_t)n*F32);
        const float4* xc4 = (const float4*)s_xc;
        #pragma unroll
        for (int c = 0; c < F32/4; ++c) {
            float4 xf = xfg[c];
            #pragma unroll
            for (int li = 0; li < LPB; ++li)
                cd[li] += sqd4(xf, xc4[li*(F32/4) + c]);
        }
        #pragma unroll
        for (int li = 0; li < LPB; ++li) {
            float tc = atan_inv(cd[li]) - HPI;
            float total = pt[li] + tc*tc;
            out[(size_t)(l0 + li)*N + n] = atan_inv(total);
        }
    }
}

extern "C" void kernel_launch(void* const* d_in, const int* in_sizes, int n_in,
                              void* d_out, int out_size, void* d_ws, size_t ws_size,
                              hipStream_t stream) {
    const float* x_focal            = (const float*)d_in[0];
    const float* p_focal            = (const float*)d_in[1];
    const float* x_neighbor         = (const float*)d_in[2];
    const float* p_neighbor         = (const float*)d_in[3];
    const float* edge_attr_neighbor = (const float*)d_in[4];
    const float* x_center           = (const float*)d_in[5];
    const float* x_support          = (const float*)d_in[6];
    const float* edge_attr_support  = (const float*)d_in[7];
    const float* p_support          = (const float*)d_in[8];
    float* outp = (float*)d_out;

    const int N = in_sizes[0] / F32;        // x_focal is [N, 32]
    dim3 grid((N + BLOCK - 1) / BLOCK, LSPLIT);
    hipLaunchKernelGGL(kconv_kernel, grid, dim3(BLOCK), 0, stream,
                       x_focal, p_focal, x_neighbor, p_neighbor, edge_attr_neighbor,
                       x_center, x_support, edge_attr_support, p_support, outp, N);
}

// Round 5
// 322.573 us; speedup vs baseline: 4.0685x; 1.3016x over previous
//
#include <hip/hip_runtime.h>
#include <math.h>
#include <stdint.h>
#include <stddef.h>

#define BLOCK  256
#define S4     4
#define F32    32
#define E16    16
#define E16P   20               // padded LDS row (spreads perm-gathered reads)
#define LTOT   32
#define LSPLIT 8
#define LPB    (LTOT / LSPLIT)  // 4 kernels per block
#define EPSF   1e-8f
#define HPI    1.57079632679489662f

__device__ __forceinline__ float dot4(const float4 a, const float4 b) {
    return a.x*b.x + a.y*b.y + a.z*b.z + a.w*b.w;
}
__device__ __forceinline__ float sqd4(const float4 a, const float4 b) {
    float x = a.x-b.x, y = a.y-b.y, z = a.z-b.z, w = a.w-b.w;
    return x*x + y*y + z*z + w*w;
}
// d >= 0; d == 0 -> 1/0 = +inf -> atanf(inf) = pi/2 (matches jnp.arctan)
__device__ __forceinline__ float atan_inv(float d) {
    return atanf(1.0f / d);
}

// R2: (256,4) -> 64 VGPR + 2.4GB spill. R3: acc[4][4][4] cross-l + hoisted
// loads -> 128 VGPR + 1.2GB spill (allocator spills to hold the 128 tier).
// R4: sequential-l, per-l live set ~80 regs -> must be spill-free.
__global__ __launch_bounds__(BLOCK, 2)
void kconv_kernel(const float* __restrict__ x_focal,
                  const float* __restrict__ p_focal,
                  const float* __restrict__ x_neighbor,
                  const float* __restrict__ p_neighbor,
                  const float* __restrict__ edge_attr_neighbor,
                  const float* __restrict__ x_center,
                  const float* __restrict__ x_support,
                  const float* __restrict__ edge_attr_support,
                  const float* __restrict__ p_support,
                  float* __restrict__ out, int N)
{
    // ---- L-side tables for THIS block's LPB kernels only (~4 KB LDS) ----
    __shared__ float s_xsup [LPB*S4*F32];   // 2 KB
    __shared__ float s_esup [LPB*S4*E16P];  // 1.25 KB (padded rows)
    __shared__ float s_xc   [LPB*F32];      // 0.5 KB
    __shared__ float s_sqsup[LPB];
    __shared__ float s_ncos [LPB*16];       // pairwise cos table
    __shared__ float s_nrm  [LPB*S4];

    const int tid = threadIdx.x;
    const int l0  = blockIdx.y * LPB;

    for (int i = tid; i < LPB*S4*F32/4; i += BLOCK)
        ((float4*)s_xsup)[i] = ((const float4*)(x_support + l0*S4*F32))[i];
    for (int i = tid; i < LPB*S4*(E16/4); i += BLOCK) {
        const int row = i / (E16/4), c = i % (E16/4);
        ((float4*)(s_esup + row*E16P))[c] =
            ((const float4*)(edge_attr_support + (l0*S4 + row)*E16))[c];
    }
    for (int i = tid; i < LPB*F32/4; i += BLOCK)
        ((float4*)s_xc)[i] = ((const float4*)(x_center + l0*F32))[i];

    if (tid < LPB) {
        const int l = l0 + tid;
        float s = 0.f;
        const float4* xs = (const float4*)(x_support + l*(S4*F32));
        #pragma unroll
        for (int c = 0; c < S4*F32/4; ++c) { float4 v = xs[c]; s += dot4(v, v); }
        s_sqsup[tid] = s;

        float ps[S4][3];
        #pragma unroll
        for (int q = 0; q < S4; ++q)
            #pragma unroll
            for (int k = 0; k < 3; ++k)
                ps[q][k] = p_support[(l*S4 + q)*3 + k];
        float nr[S4], nc[S4];
        #pragma unroll
        for (int q = 0; q < S4; ++q) {
            nr[q] = sqrtf(ps[q][0]*ps[q][0] + ps[q][1]*ps[q][1] + ps[q][2]*ps[q][2]);
            s_nrm[tid*S4 + q] = nr[q];
            nc[q] = fmaxf(nr[q], EPSF);
        }
        #pragma unroll
        for (int a = 0; a < S4; ++a)
            #pragma unroll
            for (int b = 0; b < S4; ++b) {
                float d = ps[a][0]*ps[b][0] + ps[a][1]*ps[b][1] + ps[a][2]*ps[b][2];
                s_ncos[tid*16 + a*4 + b] = d / (nc[a]*nc[b]);
            }
    }
    __syncthreads();

    const int n = blockIdx.x * BLOCK + tid;
    if (n >= N) return;                     // no barriers after this point

    // ---- geometry (small persistent state: len_nei, inn, sq_nei) ----
    float len_nei[S4], inn[S4];
    {
        float pf[3], pnv[S4][3];
        #pragma unroll
        for (int k = 0; k < 3; ++k) pf[k] = p_focal[n*3 + k];
        #pragma unroll
        for (int s = 0; s < S4; ++s)
            #pragma unroll
            for (int k = 0; k < 3; ++k)
                pnv[s][k] = p_neighbor[((size_t)n*S4 + s)*3 + k] - pf[k];
        #pragma unroll
        for (int s = 0; s < S4; ++s)
            len_nei[s] = sqrtf(pnv[s][0]*pnv[s][0] + pnv[s][1]*pnv[s][1] + pnv[s][2]*pnv[s][2]);
        #pragma unroll
        for (int s = 0; s < S4; ++s) {
            const int a = (s + 3) & 3;      // roll(+1): q[s] = p[s-1]
            float d = pnv[a][0]*pnv[s][0] + pnv[a][1]*pnv[s][1] + pnv[a][2]*pnv[s][2];
            inn[s] = d / (fmaxf(len_nei[a], EPSF) * fmaxf(len_nei[s], EPSF));
        }
    }

    const float4* xng = (const float4*)(x_neighbor + (size_t)n*(S4*F32));
    const float4* evg = (const float4*)(edge_attr_neighbor + (size_t)n*(S4*E16));
    const float4* xfg = (const float4*)(x_focal + (size_t)n*F32);

    float sq_nei = 0.f;
    #pragma unroll 4
    for (int i = 0; i < S4*F32/4; ++i) { float4 v = xng[i]; sq_nei += dot4(v, v); }

    // lexicographic permutations of (0,1,2,3) (itertools.permutations order)
    constexpr int PERM[24][4] = {
        {0,1,2,3},{0,1,3,2},{0,2,1,3},{0,2,3,1},{0,3,1,2},{0,3,2,1},
        {1,0,2,3},{1,0,3,2},{1,2,0,3},{1,2,3,0},{1,3,0,2},{1,3,2,0},
        {2,0,1,3},{2,0,3,1},{2,1,0,3},{2,1,3,0},{2,3,0,1},{2,3,1,0},
        {3,0,1,2},{3,0,2,1},{3,1,0,2},{3,1,2,0},{3,2,0,1},{3,2,1,0}
    };

    // ================= sequential over this block's l's =================
    #pragma unroll 1
    for (int li = 0; li < LPB; ++li) {

        // ---- 4x4 pairwise dots; xn re-streamed from L1/L2 (512 B) ----
        float acc[S4][S4];
        #pragma unroll
        for (int s = 0; s < S4; ++s)
            #pragma unroll
            for (int t = 0; t < S4; ++t) acc[s][t] = 0.f;

        const float4* supb = (const float4*)(s_xsup + li*(S4*F32));
        #pragma unroll 4
        for (int c = 0; c < F32/4; ++c) {
            float4 xv0 = xng[0*(F32/4) + c];
            float4 xv1 = xng[1*(F32/4) + c];
            float4 xv2 = xng[2*(F32/4) + c];
            float4 xv3 = xng[3*(F32/4) + c];
            #pragma unroll
            for (int t = 0; t < S4; ++t) {
                float4 sv = supb[t*(F32/4) + c];   // wave-uniform LDS: broadcast
                acc[0][t] += dot4(xv0, sv);
                acc[1][t] += dot4(xv1, sv);
                acc[2][t] += dot4(xv2, sv);
                acc[3][t] += dot4(xv3, sv);
            }
        }

        // ---- fold 24 perms: argmin d, first occurrence ----
        const float base = sq_nei + s_sqsup[li];
        float best_d = 3.4e38f;
        uint32_t best_pk = 0u;
        #pragma unroll
        for (int p = 0; p < 24; ++p) {
            float cross = acc[0][PERM[p][0]] + acc[1][PERM[p][1]]
                        + acc[2][PERM[p][2]] + acc[3][PERM[p][3]];
            float d = fmaxf(base - 2.0f*cross, 0.0f);
            uint32_t pk = (uint32_t)PERM[p][0] | ((uint32_t)PERM[p][1] << 8)
                        | ((uint32_t)PERM[p][2] << 16) | ((uint32_t)PERM[p][3] << 24);
            if (d < best_d) { best_d = d; best_pk = pk; }
        }
        const float sup_sc = atan_inv(best_d);

        const int pm0 = (int)( best_pk        & 3u);
        const int pm1 = (int)((best_pk >> 8)  & 3u);
        const int pm2 = (int)((best_pk >> 16) & 3u);
        const int pm3 = (int)((best_pk >> 24) & 3u);

        // ---- angle score ----
        float ad;
        {
            const float* nc = s_ncos + li*16;
            float d0 = inn[0] - nc[pm3*4 + pm0];   // a = (s+3)&3
            float d1 = inn[1] - nc[pm0*4 + pm1];
            float d2 = inn[2] - nc[pm1*4 + pm2];
            float d3 = inn[3] - nc[pm2*4 + pm3];
            ad = d0*d0 + d1*d1 + d2*d2 + d3*d3;
        }
        const float ang_sc = atan_inv(ad);

        // ---- length score ----
        float ldist;
        {
            const float* nr = s_nrm + li*S4;
            float d0 = len_nei[0] - nr[pm0];
            float d1 = len_nei[1] - nr[pm1];
            float d2 = len_nei[2] - nr[pm2];
            float d3 = len_nei[3] - nr[pm3];
            ldist = d0*d0 + d1*d1 + d2*d2 + d3*d3;
        }
        const float len_sc = atan_inv(ldist);

        // ---- edge score: ev re-streamed (256 B, cache-hot), rows from LDS ----
        float edist = 0.f;
        {
            const int pm[S4] = {pm0, pm1, pm2, pm3};
            #pragma unroll
            for (int s = 0; s < S4; ++s) {
                const float4* er = (const float4*)(s_esup + (li*S4 + pm[s])*E16P);
                float4 e0 = evg[s*(E16/4) + 0];
                float4 e1 = evg[s*(E16/4) + 1];
                float4 e2 = evg[s*(E16/4) + 2];
                float4 e3 = evg[s*(E16/4) + 3];
                edist += sqd4(e0, er[0]) + sqd4(e1, er[1])
                       + sqd4(e2, er[2]) + sqd4(e3, er[3]);
            }
        }
        const float edg_sc = atan_inv(edist);

        // ---- center score: xf re-streamed (128 B, cache-hot) ----
        float cd = 0.f;
        {
            const float4* xc4 = (const float4*)(s_xc + li*F32);
            #pragma unroll 4
            for (int c = 0; c < F32/4; ++c) cd += sqd4(xfg[c], xc4[c]);
        }
        const float cen_sc = atan_inv(cd);

        // ---- total ----
        float t0 = len_sc - HPI, t1 = ang_sc - HPI, t2 = sup_sc - HPI,
              t3 = cen_sc - HPI, t4 = edg_sc - HPI;
        float total = t0*t0 + t1*t1 + t2*t2 + t3*t3 + t4*t4;
        out[(size_t)(l0 + li)*N + n] = atan_inv(total);
    }
}

extern "C" void kernel_launch(void* const* d_in, const int* in_sizes, int n_in,
                              void* d_out, int out_size, void* d_ws, size_t ws_size,
                              hipStream_t stream) {
    const float* x_focal            = (const float*)d_in[0];
    const float* p_focal            = (const float*)d_in[1];
    const float* x_neighbor         = (const float*)d_in[2];
    const float* p_neighbor         = (const float*)d_in[3];
    const float* edge_attr_neighbor = (const float*)d_in[4];
    const float* x_center           = (const float*)d_in[5];
    const float* x_support          = (const float*)d_in[6];
    const float* edge_attr_support  = (const float*)d_in[7];
    const float* p_support          = (const float*)d_in[8];
    float* outp = (float*)d_out;

    const int N = in_sizes[0] / F32;        // x_focal is [N, 32]
    dim3 grid((N + BLOCK - 1) / BLOCK, LSPLIT);
    hipLaunchKernelGGL(kconv_kernel, grid, dim3(BLOCK), 0, stream,
                       x_focal, p_focal, x_neighbor, p_neighbor, edge_attr_neighbor,
                       x_center, x_support, edge_attr_support, p_support, outp, N);
}